// Round 2
// baseline (495.746 us; speedup 1.0000x reference)
//
#include <hip/hip_runtime.h>
#include <cstddef>

// DynamicNetwork via split-bf16 MFMA (hi/lo, 3 MFMA per product).
// R8: algebraic fusion — nodes 2..5 never materialized.
//   h_0 = relu([node0|node1] @ [s1 Pd; s2 Ps] + C_0)
//   h_i = relu([h_{i-1}|node1] @ [M_i; s1_i Ps] + C_i),  M_i = s2_i sk_{i-1} (Wc_{i-1}@Pb)
//   logits = sum_i h_i @ gv_i + const,                  gv_i = sk_i Wc_i @ clf_w_i
// R9: prepvec re-parallelized (grid 4x512 -> 56x256).
// R10: mfma_gemm rebuilt: BM64xBN128 grid-512 (2 blocks/CU, 4 waves/SIMD),
//      global_load_lds direct staging (no reg round-trip), linear conflict-free
//      LDS, 4-way k-split + LDS partial reduce. prep1 re-parallelized (39 blocks).

typedef short short8 __attribute__((ext_vector_type(8)));
typedef float floatx16 __attribute__((ext_vector_type(16)));

#define EMB_BLOCKS 832
#define SN0 224   // node0 k-stride (208 used)
#define SN1 448   // node1 k-stride (416 used)
#define SH  416   // hidden k-stride (400 used)

__device__ __forceinline__ unsigned short f2bf(float f) {
    unsigned int u = __float_as_uint(f);
    u += 0x7fffu + ((u >> 16) & 1u);
    return (unsigned short)(u >> 16);
}
__device__ __forceinline__ float bf2f(unsigned short h) {
    return __uint_as_float((unsigned int)h << 16);
}
__device__ __forceinline__ void split2(float v, unsigned short& h, unsigned short& l) {
    h = f2bf(v);
    l = f2bf(v - bf2f(h));
}

__device__ __forceinline__ void async16(unsigned short* l, const unsigned short* g) {
    __builtin_amdgcn_global_load_lds(
        (const __attribute__((address_space(1))) unsigned int*)g,
        (__attribute__((address_space(3))) unsigned int*)l,
        16, 0, 0);
}

// ---------------- prep1: column sums (39 blocks) + alpha scalars ----------------
// grid dim3(13,3): y = matrix (Pd/Ps/Pb), x = 32-col chunk. 256 thr = 32 cols x 8 k-groups.
__global__ __launch_bounds__(256) void prep1_kernel(
    const float* __restrict__ Pd, const float* __restrict__ Ps, const float* __restrict__ Pb,
    const float* __restrict__ a0, const float* __restrict__ a1,
    const float* __restrict__ a2, const float* __restrict__ a3,
    float* __restrict__ scal,
    float* __restrict__ csd, float* __restrict__ css, float* __restrict__ csb)
{
    int t = threadIdx.x;
    int y = blockIdx.y;
    int c = t & 31, rg = t >> 5;
    int col = blockIdx.x * 32 + c;
    const float* src = (y==0) ? Pd : (y==1) ? Ps : Pb;
    int K = (y==0) ? 208 : (y==1) ? 416 : 400;
    float* out = (y==0) ? csd : (y==1) ? css : csb;
    float s = 0.f;
    if (col < 400)
        for (int k = rg; k < K; k += 8) s += src[(size_t)k*400 + col];
    __shared__ float red[8][32];
    red[rg][c] = s;
    __syncthreads();
    if (rg == 0 && col < 400) {
        float tot = 0.f;
        #pragma unroll
        for (int r = 0; r < 8; ++r) tot += red[r][c];
        out[col] = tot;
    }
    if (blockIdx.x == 0 && y == 0 && t < 4) {
        int i = t;
        const float* a = (i==0) ? a0 : (i==1) ? a1 : (i==2) ? a2 : a3;
        int np = 2 + i;
        float sum1 = 0.f, sum2 = 0.f, sumc = 0.f;
        for (int j = 0; j < np; ++j) { sum1 += a[j]; sum2 += a[np+j]; }
        for (int j = 0; j < 4; ++j) sumc += a[2*np+j];
        int i1 = (i==0) ? 0 : 1;
        int i2 = i + 1;
        int kk = i;
        float s1 = a[i1],      c1 = sum1 - s1;
        float s2 = a[np+i2],   c2 = sum2 - s2;
        float sk = a[2*np+kk], ck = sumc - sk;
        float* sl = scal + i*8;
        if (i == 0) { sl[0]=s1; sl[1]=c1; sl[2]=s2; sl[3]=c2; }
        else        { sl[0]=s2; sl[1]=c2; sl[2]=s1; sl[3]=c1; }
        sl[4] = sk; sl[5] = ck;
        (void)i2;
    }
}

// ---------------- prep2: Ps/Pd regions of weight planes [2][512][Kw] ----------------
__global__ __launch_bounds__(256) void prep2_kernel(
    const float* __restrict__ Pd, const float* __restrict__ Ps,
    const float* __restrict__ Pb,
    const float* __restrict__ scal,
    unsigned short* __restrict__ w0, unsigned short* __restrict__ w1,
    unsigned short* __restrict__ w2, unsigned short* __restrict__ w3)
{
    int z = blockIdx.z;
    int Kp = (z==0) ? 624 : 816;
    int KA = (z==0) ? 208 : 400;
    int Kw = (z==0) ? 640 : 832;
    const float* sA = (z==0) ? Pd : Pb;
    const float* sB = Ps;
    float sc1 = scal[z*8+0];
    float sc2 = scal[z*8+2];
    unsigned short* dst = (z==0) ? w0 : (z==1) ? w1 : (z==2) ? w2 : w3;

    int ktiles = (Kp + 63) >> 6;
    if ((int)blockIdx.y >= ktiles) return;
    int k0 = blockIdx.y * 64, n0 = blockIdx.x * 64;
    __shared__ float T[64][65];
    int t = threadIdx.x;
    {
        int kr = t >> 2, c0 = (t & 3) * 16;
        int gk = k0 + kr;
        bool kok = gk < Kp;
        const float* src; int srow; float sc;
        if (gk < KA) { src = sA; srow = gk; sc = sc1; }
        else         { src = sB; srow = gk - KA; sc = sc2; }
        for (int j = 0; j < 16; j += 4) {
            int n = n0 + c0 + j;
            float4 v = make_float4(0.f,0.f,0.f,0.f);
            if (kok && n < 400) v = *(const float4*)&src[(size_t)srow*400 + n];
            T[kr][c0+j+0] = v.x * sc;
            T[kr][c0+j+1] = v.y * sc;
            T[kr][c0+j+2] = v.z * sc;
            T[kr][c0+j+3] = v.w * sc;
        }
    }
    __syncthreads();
    {
        int nr = t >> 2, kc0 = (t & 3) * 16;
        int gn = n0 + nr;
        int gk0 = k0 + kc0;
        if (gk0 >= Kp) return;
        if (z > 0 && gk0 < 400) return;   // M-region written by prepM
        unsigned short hb[16], lb[16];
        for (int j = 0; j < 16; ++j) {
            float v = (gn < 400) ? T[kc0+j][nr] : 0.f;
            split2(v, hb[j], lb[j]);
        }
        unsigned short* dh = dst + (size_t)gn*Kw + gk0;
        unsigned short* dl = dst + (size_t)512*Kw + (size_t)gn*Kw + gk0;
        *(uint4*)&dh[0] = *(uint4*)&hb[0]; *(uint4*)&dh[8] = *(uint4*)&hb[8];
        *(uint4*)&dl[0] = *(uint4*)&lb[0]; *(uint4*)&dl[8] = *(uint4*)&lb[8];
    }
}

// ---------------- prepM: M_g = s2_g * sk_{g-1} * (Wc_{g-1} @ Pb), g = z+1 ----------------
__global__ __launch_bounds__(256) void prepM_kernel(
    const float* __restrict__ Wc, const float* __restrict__ Pb,
    const float* __restrict__ scal,
    unsigned short* __restrict__ w1, unsigned short* __restrict__ w2,
    unsigned short* __restrict__ w3)
{
    int z = blockIdx.z;                   // 0..2 -> GEMM g = z+1
    unsigned short* dst = (z==0) ? w1 : (z==1) ? w2 : w3;
    const float* A = Wc + (size_t)z*5*160000;   // Wc[z, kk=z] : [400k][400j]
    float scale = scal[(z+1)*8+0] * scal[z*8+4];
    const int Kw = 832;

    __shared__ float As[16][68];   // [j][k]
    __shared__ float Ws[16][68];   // [j][n]
    int t = threadIdx.x;
    int tx = t & 15, ty = t >> 4;
    int bk = blockIdx.y * 64;
    int bn = blockIdx.x * 64;
    int arow = t >> 2;
    int aj4  = (t & 3) << 2;
    int wrow = t >> 4;
    int wc4  = (t & 15) << 2;
    float acc[4][4] = {};
    for (int j0 = 0; j0 < 400; j0 += 16) {
        float4 av = make_float4(0.f,0.f,0.f,0.f);
        if (bk + arow < 400) av = *(const float4*)&A[(size_t)(bk+arow)*400 + j0 + aj4];
        float4 wv = make_float4(0.f,0.f,0.f,0.f);
        if (bn + wc4 < 400) wv = *(const float4*)&Pb[(size_t)(j0+wrow)*400 + bn + wc4];
        __syncthreads();
        As[aj4+0][arow] = av.x;
        As[aj4+1][arow] = av.y;
        As[aj4+2][arow] = av.z;
        As[aj4+3][arow] = av.w;
        *(float4*)&Ws[wrow][wc4] = wv;
        __syncthreads();
        #pragma unroll
        for (int jj = 0; jj < 16; ++jj) {
            float4 a4 = *(const float4*)&As[jj][ty<<2];
            float4 b4 = *(const float4*)&Ws[jj][tx<<2];
            acc[0][0] += a4.x*b4.x; acc[0][1] += a4.x*b4.y; acc[0][2] += a4.x*b4.z; acc[0][3] += a4.x*b4.w;
            acc[1][0] += a4.y*b4.x; acc[1][1] += a4.y*b4.y; acc[1][2] += a4.y*b4.z; acc[1][3] += a4.y*b4.w;
            acc[2][0] += a4.z*b4.x; acc[2][1] += a4.z*b4.y; acc[2][2] += a4.z*b4.z; acc[2][3] += a4.z*b4.w;
            acc[3][0] += a4.w*b4.x; acc[3][1] += a4.w*b4.y; acc[3][2] += a4.w*b4.z; acc[3][3] += a4.w*b4.w;
        }
    }
    int gk0 = bk + (ty << 2);
    int gn0 = bn + (tx << 2);
    #pragma unroll
    for (int ik = 0; ik < 4; ++ik) {
        int gk = gk0 + ik;
        if (gk >= 400) break;
        #pragma unroll
        for (int in = 0; in < 4; ++in) {
            int gn = gn0 + in;
            float v = (gn < 400) ? acc[ik][in] * scale : 0.f;
            unsigned short h16, l16; split2(v, h16, l16);
            dst[(size_t)gn*Kw + gk] = h16;
            dst[(size_t)512*Kw + (size_t)gn*Kw + gk] = l16;
        }
    }
}

// ---------------- prepvec: C_i, gv_i, scalar consts (R9: 56 blocks) ----------------
__global__ __launch_bounds__(256) void prepvec_kernel(
    const float* __restrict__ scal,
    const float* __restrict__ csd, const float* __restrict__ css, const float* __restrict__ csb,
    const float* __restrict__ Wc, const float* __restrict__ bc,
    const float* __restrict__ clf_w, const float* __restrict__ Pb,
    float* __restrict__ cv, float* __restrict__ gv, float* __restrict__ scl2)
{
    int i = blockIdx.y;
    int tid = threadIdx.x;
    int tbase = blockIdx.x * 32;
    const float* cw = clf_w + i*400;
    float ski = scal[i*8+4], cki = scal[i*8+5];
    const float* A = Wc + (size_t)i*5*160000;

    int wv = tid >> 6, lane = tid & 63;
    #pragma unroll
    for (int q = 0; q < 8; ++q) {
        int t = tbase + wv*8 + q;
        float s = 0.f;
        if (t < 400) {
            const float* wr = A + (size_t)t*400;
            for (int j = lane; j < 400; j += 64) s += wr[j]*cw[j];
            #pragma unroll
            for (int o = 32; o > 0; o >>= 1) s += __shfl_xor(s, o);
        }
        if (lane == 0) gv[i*448 + t] = (t < 400) ? ski * s : 0.f;
    }

    __shared__ float bpred[8][32];
    int t = tbase + (tid & 31);
    int jc = tid >> 5;
    float bp_part = 0.f;
    if (i > 0 && t < 400) {
        const float* bcp = bc + (size_t)(i-1)*5*400;
        for (int j = jc*50; j < jc*50 + 50; ++j)
            bp_part += bcp[j] * Pb[(size_t)j*400 + t];
    }
    bpred[jc][tid & 31] = bp_part;
    __syncthreads();
    if (tid < 32) {
        float bp = 0.f;
        #pragma unroll
        for (int r = 0; r < 8; ++r) bp += bpred[r][tid];
        float c = 0.f;
        if (t < 400) {
            if (i == 0) {
                c = scal[1]*csd[t] + scal[3]*css[t];
            } else {
                float s2 = scal[i*8+0], c2 = scal[i*8+1];
                float c1 = scal[i*8+3];
                float skp = scal[(i-1)*8+4], ckp = scal[(i-1)*8+5];
                c = c1*css[t] + (c2 + s2*ckp)*csb[t] + s2*skp*bp;
            }
        }
        cv[i*448 + t] = c;
    }

    if (blockIdx.x == 0) {
        const float* bci = bc + (size_t)i*5*400;
        float sc = 0.f;
        for (int j = tid; j < 400; j += 256) sc += (ski*bci[j] + cki)*cw[j];
        #pragma unroll
        for (int o = 32; o > 0; o >>= 1) sc += __shfl_down(sc, o);
        __shared__ float red[4];
        int wv2 = tid >> 6, ln = tid & 63;
        if (ln == 0) red[wv2] = sc;
        __syncthreads();
        if (tid == 0) scl2[i] = red[0]+red[1]+red[2]+red[3];
    }
}

// ---------------- embed: node0/node1 bf16 hi/lo planes (padded strides) ----------------
__global__ __launch_bounds__(256) void embed_kernel(
    const float* __restrict__ rd, const int* __restrict__ rs,
    const float* __restrict__ emb,
    unsigned short* __restrict__ n0h, unsigned short* __restrict__ n0l,
    unsigned short* __restrict__ n1h, unsigned short* __restrict__ n1l,
    float* __restrict__ partial)
{
    int tid0 = blockIdx.x*256 + threadIdx.x;
    int nth = gridDim.x*256;
    float ssq = 0.f, dsq = 0.f;
    for (int it = tid0; it < 8192*26; it += nth) {
        int b = it / 26, s = it - b*26;
        int row = 13 + 50000*s + rs[b*26 + s];
        const float* e = emb + (size_t)row*16;
        float4 e0 = *(const float4*)&e[0], e1 = *(const float4*)&e[4];
        float4 e2 = *(const float4*)&e[8], e3 = *(const float4*)&e[12];
        float vv[16] = {e0.x,e0.y,e0.z,e0.w, e1.x,e1.y,e1.z,e1.w,
                        e2.x,e2.y,e2.z,e2.w, e3.x,e3.y,e3.z,e3.w};
        unsigned short hb[16], lb[16];
        for (int j = 0; j < 16; ++j) { ssq += vv[j]*vv[j]; split2(vv[j], hb[j], lb[j]); }
        size_t off = (size_t)b*SN1 + s*16;
        *(uint4*)&n1h[off] = *(uint4*)&hb[0]; *(uint4*)&n1h[off+8] = *(uint4*)&hb[8];
        *(uint4*)&n1l[off] = *(uint4*)&lb[0]; *(uint4*)&n1l[off+8] = *(uint4*)&lb[8];
    }
    for (int it = tid0; it < 8192*13; it += nth) {
        int b = it / 13, f = it - b*13;
        float sc = rd[b*13 + f];
        const float* e = emb + (size_t)f*16;
        float4 e0 = *(const float4*)&e[0], e1 = *(const float4*)&e[4];
        float4 e2 = *(const float4*)&e[8], e3 = *(const float4*)&e[12];
        float vv[16] = {e0.x,e0.y,e0.z,e0.w, e1.x,e1.y,e1.z,e1.w,
                        e2.x,e2.y,e2.z,e2.w, e3.x,e3.y,e3.z,e3.w};
        unsigned short hb[16], lb[16];
        for (int j = 0; j < 16; ++j) { float v = vv[j]*sc; dsq += v*v; split2(v, hb[j], lb[j]); }
        size_t off = (size_t)b*SN0 + f*16;
        *(uint4*)&n0h[off] = *(uint4*)&hb[0]; *(uint4*)&n0h[off+8] = *(uint4*)&hb[8];
        *(uint4*)&n0l[off] = *(uint4*)&lb[0]; *(uint4*)&n0l[off+8] = *(uint4*)&lb[8];
    }
    for (int o = 32; o > 0; o >>= 1) { ssq += __shfl_down(ssq, o); dsq += __shfl_down(dsq, o); }
    __shared__ float red[8];
    int wave = threadIdx.x >> 6, lane = threadIdx.x & 63;
    if (lane == 0) { red[wave] = dsq; red[4+wave] = ssq; }
    __syncthreads();
    if (threadIdx.x == 0) {
        partial[blockIdx.x*2]   = red[0]+red[1]+red[2]+red[3];
        partial[blockIdx.x*2+1] = red[4]+red[5]+red[6]+red[7];
    }
}

// blocks 0..31: out[b] = clf_b + sum_i scl2[i]; block 32: regs
__global__ __launch_bounds__(256) void finalize_kernel(
    const float* __restrict__ clf_b, const float* __restrict__ partial,
    const float* __restrict__ scl2, float* __restrict__ out)
{
    if (blockIdx.x < 32) {
        float base = clf_b[0] + scl2[0] + scl2[1] + scl2[2] + scl2[3];
        out[blockIdx.x*256 + threadIdx.x] = base;
        return;
    }
    float d = 0.f, s = 0.f;
    for (int i = threadIdx.x; i < EMB_BLOCKS; i += 256) { d += partial[2*i]; s += partial[2*i+1]; }
    for (int o = 32; o > 0; o >>= 1) { d += __shfl_down(d, o); s += __shfl_down(s, o); }
    __shared__ float red[8];
    int wave = threadIdx.x >> 6, lane = threadIdx.x & 63;
    if (lane == 0) { red[wave] = d; red[4+wave] = s; }
    __syncthreads();
    if (threadIdx.x == 0) {
        float dd = red[0]+red[1]+red[2]+red[3];
        float ss = red[4]+red[5]+red[6]+red[7];
        out[8192] = 1e-5f * (sqrtf(dd) + sqrtf(ss));
    }
}

// ---------------- R10 MFMA GEMM: BM64 x BN128 x BK16, global_load_lds ----------------
// Grid 512 = 128 mt x 4 nt (XCD swizzle) -> 2 blocks/CU, 4 waves/SIMD.
// 8 waves: kw = W&3 (4-way k-split over steps), nw = W>>2 (64-col half).
// LDS per buf (6144 shorts): A[2pl][64][16] (4KB) | B[2pl][128][16] (8KB). Linear,
// stride 32B; b128 fragment reads are conflict-free (hh halves pack each row).
// Staging: 12 x global_load_lds dwordx4 per step (waves 0-3: 1 A + 1 B; 4-7: 1 B).
// Epilogue: 4-partial LDS reduce (24KB float region = exactly both bufs).
__global__ __launch_bounds__(512, 4) void mfma_gemm(
    const unsigned short* __restrict__ a1h, const unsigned short* __restrict__ a1l, int sA, int KA,
    const unsigned short* __restrict__ a2h, const unsigned short* __restrict__ a2l,
    const unsigned short* __restrict__ bph, int Kp, int Kw,
    const float* __restrict__ vec,
    unsigned short* __restrict__ ch, unsigned short* __restrict__ cl,
    const float* __restrict__ lw, float* __restrict__ lout)
{
    __shared__ __align__(16) unsigned short smem[2][6144];

    int tid = threadIdx.x;
    int bid = blockIdx.x;
    int xcd = bid & 7, idx = bid >> 3;
    int mt = xcd*16 + (idx >> 2);
    int nt = idx & 3;
    int bm = mt * 64, bn = nt * 128;

    int W = tid >> 6, lane = tid & 63;
    int kw = W & 3, nw = W >> 2;
    int r31 = lane & 31, hh = lane >> 5;

    int nk = Kp >> 4;

    floatx16 acc00, acc01, acc10, acc11;
    for (int i = 0; i < 16; ++i) { acc00[i]=0.f; acc01[i]=0.f; acc10[i]=0.f; acc11[i]=0.f; }

    // DMA roles
    int pA = W >> 1, rA = (W & 1) * 32;          // waves 0..3: A chunk
    int pB = W >> 2, rB = (W & 3) * 32;          // all waves: B chunk
    int lrow = lane >> 1, lk = (lane & 1) * 8;
    const unsigned short* A1p = (pA ? a1l : a1h);
    const unsigned short* A2p = (pA ? a2l : a2h);
    size_t a1off = (size_t)(bm + rA + lrow) * sA + lk;
    size_t a2off = (size_t)(bm + rA + lrow) * SN1 + lk;
    const unsigned short* Bsrc = bph + (size_t)pB*512*Kw + (size_t)(bn + rB + lrow)*Kw + lk;
    unsigned short* dA = &smem[0][pA*1024 + rA*16];        // wave-uniform LDS base
    unsigned short* dB = &smem[0][2048 + pB*2048 + rB*16];

    #define ISSUE(K, BB) do {                                                  \
        int kb_ = (K) << 4;                                                    \
        if (W < 4) {                                                           \
            const unsigned short* s_ = (kb_ < KA) ? A1p + a1off + kb_          \
                                                  : A2p + a2off + (kb_ - KA); \
            async16(dA + (BB)*6144, s_);                                       \
        }                                                                      \
        async16(dB + (BB)*6144, Bsrc + kb_);                                   \
    } while (0)

    #define COMPUTE(BB) do {                                                   \
        const unsigned short* s_ = &smem[(BB)][0];                             \
        const unsigned short* pa = s_ + r31*16 + hh*8;                         \
        const unsigned short* pb = s_ + 2048 + (nw*64 + r31)*16 + hh*8;        \
        short8 va0h = *(const short8*)(pa);                                    \
        short8 va1h = *(const short8*)(pa + 512);                              \
        short8 va0l = *(const short8*)(pa + 1024);                             \
        short8 va1l = *(const short8*)(pa + 1536);                             \
        short8 vb0h = *(const short8*)(pb);                                    \
        short8 vb1h = *(const short8*)(pb + 512);                              \
        short8 vb0l = *(const short8*)(pb + 2048);                             \
        short8 vb1l = *(const short8*)(pb + 2560);                             \
        acc00 = __builtin_amdgcn_mfma_f32_32x32x16_bf16(va0h, vb0h, acc00,0,0,0);\
        acc01 = __builtin_amdgcn_mfma_f32_32x32x16_bf16(va0h, vb1h, acc01,0,0,0);\
        acc10 = __builtin_amdgcn_mfma_f32_32x32x16_bf16(va1h, vb0h, acc10,0,0,0);\
        acc11 = __builtin_amdgcn_mfma_f32_32x32x16_bf16(va1h, vb1h, acc11,0,0,0);\
        acc00 = __builtin_amdgcn_mfma_f32_32x32x16_bf16(va0h, vb0l, acc00,0,0,0);\
        acc01 = __builtin_amdgcn_mfma_f32_32x32x16_bf16(va0h, vb1l, acc01,0,0,0);\
        acc10 = __builtin_amdgcn_mfma_f32_32x32x16_bf16(va1h, vb0l, acc10,0,0,0);\
        acc11 = __builtin_amdgcn_mfma_f32_32x32x16_bf16(va1h, vb1l, acc11,0,0,0);\
        acc00 = __builtin_amdgcn_mfma_f32_32x32x16_bf16(va0l, vb0h, acc00,0,0,0);\
        acc01 = __builtin_amdgcn_mfma_f32_32x32x16_bf16(va0l, vb1h, acc01,0,0,0);\
        acc10 = __builtin_amdgcn_mfma_f32_32x32x16_bf16(va1l, vb0h, acc10,0,0,0);\
        acc11 = __builtin_amdgcn_mfma_f32_32x32x16_bf16(va1l, vb1h, acc11,0,0,0);\
    } while(0)

    int cur = 0;
    ISSUE(0, 0);
    for (int k = 0; k < nk; ++k) {
        asm volatile("s_waitcnt vmcnt(0)" ::: "memory");
        __syncthreads();
        if (k + 1 < nk) ISSUE(k + 1, cur ^ 1);
        if ((k & 3) == kw) COMPUTE(cur);
        cur ^= 1;
    }
    #undef ISSUE
    #undef COMPUTE

    __syncthreads();

    // Epilogue: reduce 4 k-partials per output quadrant, then relu/store/logits.
    float* red = (float*)&smem[0][0];   // [nw 2][src 3][lane 64][16] = 6144 floats
    int gn_base = bn + nw*64;
    #pragma unroll
    for (int q = 0; q < 4; ++q) {
        const floatx16& part = (q==0) ? acc00 : (q==1) ? acc01 : (q==2) ? acc10 : acc11;
        int a = q >> 1, b = q & 1;
        if (kw != 0) {
            float* dst = red + ((nw*3 + (kw-1))*64 + lane)*16;
            #pragma unroll
            for (int j4 = 0; j4 < 4; ++j4)
                *(float4*)(dst + j4*4) = make_float4(part[j4*4+0],part[j4*4+1],part[j4*4+2],part[j4*4+3]);
        }
        __syncthreads();
        if (kw == 0) {
            const float* s0 = red + (nw*3*64 + lane)*16;
            int gn = gn_base + b*32 + r31;
            bool ok = gn < 400;
            float vc = ok ? vec[gn] : 0.f;
            float wvv = ok ? lw[gn] : 0.f;
            #pragma unroll
            for (int j = 0; j < 16; ++j) {
                float v = part[j] + s0[j] + s0[1024 + j] + s0[2048 + j] + vc;
                v = fmaxf(v, 0.f);
                int gm = bm + a*32 + (j & 3) + 8*(j >> 2) + 4*hh;
                if (ch && ok) {
                    unsigned short h16, l16; split2(v, h16, l16);
                    ch[(size_t)gm*SH + gn] = h16;
                    cl[(size_t)gm*SH + gn] = l16;
                }
                float lv = v*wvv;
                #pragma unroll
                for (int o = 1; o < 32; o <<= 1) lv += __shfl_xor(lv, o);
                if (r31 == 0) atomicAdd(&lout[gm], lv);
            }
        }
        __syncthreads();
    }
}

// ---------------- host ----------------
static inline size_t align64(size_t x) { return (x + 63) & ~(size_t)63; }

extern "C" void kernel_launch(void* const* d_in, const int* in_sizes, int n_in,
                              void* d_out, int out_size, void* d_ws, size_t ws_size,
                              hipStream_t stream)
{
    const float* raw_dense  = (const float*)d_in[0];
    const int*   raw_sparse = (const int*)d_in[1];
    const float* emb   = (const float*)d_in[2];
    const float* Pd    = (const float*)d_in[3];
    const float* Ps    = (const float*)d_in[4];
    const float* Pb    = (const float*)d_in[5];
    const float* Wc    = (const float*)d_in[6];
    const float* bc    = (const float*)d_in[7];
    const float* clf_w = (const float*)d_in[8];
    const float* clf_b = (const float*)d_in[9];
    const float* a0 = (const float*)d_in[10];
    const float* a1 = (const float*)d_in[11];
    const float* a2 = (const float*)d_in[12];
    const float* a3 = (const float*)d_in[13];
    float* out = (float*)d_out;

    char* p = (char*)d_ws;
    auto alloc = [&](size_t bytes) { char* r = p; p += align64(bytes); return r; };

    float* scal    = (float*)alloc(32*4);
    float* partial = (float*)alloc(2*EMB_BLOCKS*4);
    float* csd     = (float*)alloc(400*4);
    float* css     = (float*)alloc(400*4);
    float* csb     = (float*)alloc(400*4);
    float* cv      = (float*)alloc(4*448*4);
    float* gv      = (float*)alloc(4*448*4);
    float* scl2    = (float*)alloc(16*4);
    unsigned short* w0 = (unsigned short*)alloc((size_t)2*512*640*2);
    unsigned short* w1 = (unsigned short*)alloc((size_t)2*512*832*2);
    unsigned short* w2 = (unsigned short*)alloc((size_t)2*512*832*2);
    unsigned short* w3 = (unsigned short*)alloc((size_t)2*512*832*2);
    unsigned short* n0h = (unsigned short*)alloc((size_t)8192*SN0*2);
    unsigned short* n0l = (unsigned short*)alloc((size_t)8192*SN0*2);
    unsigned short* n1h = (unsigned short*)alloc((size_t)8192*SN1*2);
    unsigned short* n1l = (unsigned short*)alloc((size_t)8192*SN1*2);
    unsigned short* hAh = (unsigned short*)alloc((size_t)8192*SH*2);
    unsigned short* hAl = (unsigned short*)alloc((size_t)8192*SH*2);
    unsigned short* hBh = (unsigned short*)alloc((size_t)8192*SH*2);
    unsigned short* hBl = (unsigned short*)alloc((size_t)8192*SH*2);

    prep1_kernel<<<dim3(13,3),256,0,stream>>>(Pd,Ps,Pb,a0,a1,a2,a3,scal,csd,css,csb);
    embed_kernel<<<EMB_BLOCKS,256,0,stream>>>(raw_dense, raw_sparse, emb, n0h,n0l,n1h,n1l, partial);
    prepM_kernel<<<dim3(8,7,3),256,0,stream>>>(Wc,Pb,scal,w1,w2,w3);
    prep2_kernel<<<dim3(8,13,4),256,0,stream>>>(Pd,Ps,Pb,scal,w0,w1,w2,w3);
    prepvec_kernel<<<dim3(14,4),256,0,stream>>>(scal,csd,css,csb,Wc,bc,clf_w,Pb,cv,gv,scl2);
    finalize_kernel<<<33,256,0,stream>>>(clf_b, partial, scl2, out);

    // h0 = relu([node0|node1]@w0 + cv0); logits += h0@gv0
    mfma_gemm<<<512,512,0,stream>>>(n0h,n0l,SN0,208, n1h,n1l, w0, 624,640, cv+0,    hAh,hAl, gv+0,    out);
    // h1 = relu([h0|node1]@w1 + cv1); logits += h1@gv1
    mfma_gemm<<<512,512,0,stream>>>(hAh,hAl,SH,400,  n1h,n1l, w1, 816,832, cv+448,  hBh,hBl, gv+448,  out);
    // h2
    mfma_gemm<<<512,512,0,stream>>>(hBh,hBl,SH,400,  n1h,n1l, w2, 816,832, cv+896,  hAh,hAl, gv+896,  out);
    // h3: logits only, no store
    mfma_gemm<<<512,512,0,stream>>>(hAh,hAl,SH,400,  n1h,n1l, w3, 816,832, cv+1344, nullptr,nullptr, gv+1344, out);
}